// Round 2
// baseline (233.431 us; speedup 1.0000x reference)
//
#include <hip/hip_runtime.h>

#define E_DIM 69120
#define N1 60
#define H 32
#define CC 3
#define TE 256
#define NBLK (E_DIM / TE)  // 270

// ---------------- kernel A: v_bar chain + alpha accumulation ----------------
__global__ __launch_bounds__(256) void kA(
    const float* __restrict__ d,
    const float* __restrict__ Wfvb, const float* __restrict__ bfvb,
    const float* __restrict__ Wgvb, const float* __restrict__ bgvb,
    const float* __restrict__ Wfu,  const float* __restrict__ bfu,
    float* __restrict__ alphaAcc)
{
    __shared__ float vw_l[TE][H + 1];
    const int tid = threadIdx.x;
    const long e0 = (long)blockIdx.x * TE;

    // ---- stage 1: this thread owns e = e0 + tid ----
    {
        const long e = e0 + tid;
        float wf[H], bf[H];
        #pragma unroll
        for (int h = 0; h < H; ++h) { wf[h] = Wfvb[h]; bf[h] = bfvb[h]; }
        float t1[H];
        #pragma unroll
        for (int h = 0; h < H; ++h) t1[h] = 0.f;
        for (int n = 0; n < N1; ++n) {
            const float dv = d[(long)n * E_DIM + e];
            #pragma unroll
            for (int h = 0; h < H; ++h)
                t1[h] += fmaxf(fmaf(dv, wf[h], bf[h]), 0.f);
        }
        #pragma unroll
        for (int h = 0; h < H; ++h) t1[h] *= (1.f / N1);

        float vb[H];
        #pragma unroll
        for (int h = 0; h < H; ++h) vb[h] = bgvb[h];
        #pragma unroll
        for (int k = 0; k < H; ++k) {
            const float t = t1[k];
            #pragma unroll
            for (int h = 0; h < H; ++h) vb[h] = fmaf(t, Wgvb[k * H + h], vb[h]);
        }
        #pragma unroll
        for (int h = 0; h < H; ++h) vb[h] = fmaxf(vb[h], 0.f);

        float vw[H];
        #pragma unroll
        for (int h = 0; h < H; ++h) vw[h] = bfu[h];      // fold b_fu in
        #pragma unroll
        for (int k = 0; k < H; ++k) {
            const float t = vb[k];
            #pragma unroll
            for (int h = 0; h < H; ++h) vw[h] = fmaf(t, Wfu[k * H + h], vw[h]);
        }
        #pragma unroll
        for (int h = 0; h < H; ++h) vw_l[tid][h] = vw[h];
    }
    __syncthreads();

    // ---- stage 2: threads 0..239 -> (n, h-group of 8) ----
    if (tid < N1 * 4) {
        const int n = tid >> 2, hg = tid & 3;
        float wud[8];
        #pragma unroll
        for (int j = 0; j < 8; ++j) wud[j] = Wfu[H * H + hg * 8 + j];
        float acc[8];
        #pragma unroll
        for (int j = 0; j < 8; ++j) acc[j] = 0.f;
        const float* drow = d + (long)n * E_DIM + e0;
        for (int et = 0; et < TE; et += 4) {
            const float4 d4 = *reinterpret_cast<const float4*>(drow + et);
            const float dv[4] = {d4.x, d4.y, d4.z, d4.w};
            #pragma unroll
            for (int q = 0; q < 4; ++q) {
                #pragma unroll
                for (int j = 0; j < 8; ++j)
                    acc[j] += fmaxf(fmaf(dv[q], wud[j], vw_l[et + q][hg * 8 + j]), 0.f);
            }
        }
        float* ap = alphaAcc + n * H + hg * 8;
        #pragma unroll
        for (int j = 0; j < 8; ++j) atomicAdd(&ap[j], acc[j]);
    }
}

// ---------------- kernel B: tiny chain (c_bar, beta, u_n, uwb) ----------------
__global__ __launch_bounds__(1024) void kB(
    const float* __restrict__ alphaAcc, const int* __restrict__ label,
    const float* __restrict__ Wfvb, const float* __restrict__ bfvb,
    const float* __restrict__ Wgvb, const float* __restrict__ bgvb,
    const float* __restrict__ Wfu,  const float* __restrict__ bfu,
    const float* __restrict__ Wgu,  const float* __restrict__ bgu,
    const float* __restrict__ Wfvc, const float* __restrict__ bfvc,
    float* __restrict__ uwb)
{
    __shared__ float up_l[N1 * H];
    __shared__ float un_l[N1 * H];
    __shared__ float cb_l[CC * H];
    __shared__ float cw_l[CC * H];
    __shared__ int   cnt[CC];
    const int tid = threadIdx.x;

    if (tid < CC) cnt[tid] = 0;
    __syncthreads();
    if (tid < N1) atomicAdd(&cnt[label[tid]], 1);
    __syncthreads();

    if (tid < CC * H) {
        const int c = tid / H, h = tid % H;
        const float nc = (float)cnt[c];
        float s = bgvb[h];
        #pragma unroll
        for (int k = 0; k < H; ++k) {
            const float t1c = (nc * fmaxf(Wfvb[k] + bfvb[k], 0.f) +
                               ((float)N1 - nc) * fmaxf(bfvb[k], 0.f)) * (1.f / N1);
            s = fmaf(t1c, Wgvb[k * H + h], s);
        }
        cb_l[tid] = fmaxf(s, 0.f);
    }
    __syncthreads();
    if (tid < CC * H) {
        const int c = tid / H, h = tid % H;
        float s = bfu[h];                         // fold b_fu into cw
        #pragma unroll
        for (int k = 0; k < H; ++k) s = fmaf(cb_l[c * H + k], Wfu[k * H + h], s);
        cw_l[tid] = s;
    }
    __syncthreads();
    for (int t = tid; t < N1 * H; t += 1024) {
        const int n = t >> 5, h = t & 31;
        const int ln = label[n];
        const float wud = Wfu[H * H + h];
        float s = 0.f;
        #pragma unroll
        for (int c = 0; c < CC; ++c)
            s += fmaxf(cw_l[c * H + h] + ((c == ln) ? wud : 0.f), 0.f);
        up_l[t] = alphaAcc[t] * (1.f / E_DIM) + s * (1.f / CC);
    }
    __syncthreads();
    for (int t = tid; t < N1 * H; t += 1024) {
        const int n = t >> 5, h = t & 31;
        float s = bgu[h];
        #pragma unroll
        for (int k = 0; k < H; ++k) s = fmaf(up_l[n * H + k], Wgu[k * H + h], s);
        un_l[t] = fmaxf(s, 0.f);
    }
    __syncthreads();
    for (int t = tid; t < N1 * H; t += 1024) {
        const int n = t >> 5, h = t & 31;
        float s = bfvc[h];                        // fold b_fvc into uwb
        #pragma unroll
        for (int k = 0; k < H; ++k) s = fmaf(un_l[n * H + k], Wfvc[k * H + h], s);
        uwb[t] = s;
    }
}

// ---------------- kernel C: v chain + z accumulation ----------------
__global__ __launch_bounds__(256) void kC(
    const float* __restrict__ d, const float* __restrict__ d2,
    const float* __restrict__ uwb,
    const float* __restrict__ Wfvc,
    const float* __restrict__ Wgvc, const float* __restrict__ bgvc,
    const float* __restrict__ Wfz,  const float* __restrict__ bfz,
    float* __restrict__ zAcc)
{
    __shared__ float vz_l[TE][H + 1];
    const int tid = threadIdx.x;
    const long e0 = (long)blockIdx.x * TE;

    {
        const long e = e0 + tid;
        float wvd[H];
        #pragma unroll
        for (int h = 0; h < H; ++h) wvd[h] = Wfvc[H * H + h];
        float m[H];
        #pragma unroll
        for (int h = 0; h < H; ++h) m[h] = 0.f;
        for (int n = 0; n < N1; ++n) {
            const float dv = d[(long)n * E_DIM + e];
            const float* ur = uwb + n * H;        // b_fvc already folded
            #pragma unroll
            for (int h = 0; h < H; ++h)
                m[h] += fmaxf(fmaf(dv, wvd[h], ur[h]), 0.f);
        }
        #pragma unroll
        for (int h = 0; h < H; ++h) m[h] *= (1.f / N1);

        float v[H];
        #pragma unroll
        for (int h = 0; h < H; ++h) v[h] = bgvc[h];
        #pragma unroll
        for (int k = 0; k < H; ++k) {
            const float t = m[k];
            #pragma unroll
            for (int h = 0; h < H; ++h) v[h] = fmaf(t, Wgvc[k * H + h], v[h]);
        }
        #pragma unroll
        for (int h = 0; h < H; ++h) v[h] = fmaxf(v[h], 0.f);

        float vz[H];
        #pragma unroll
        for (int h = 0; h < H; ++h) vz[h] = bfz[h];   // fold b_fz in
        #pragma unroll
        for (int k = 0; k < H; ++k) {
            const float t = v[k];
            #pragma unroll
            for (int h = 0; h < H; ++h) vz[h] = fmaf(t, Wfz[k * H + h], vz[h]);
        }
        #pragma unroll
        for (int h = 0; h < H; ++h) vz_l[tid][h] = vz[h];
    }
    __syncthreads();

    if (tid < N1 * 4) {
        const int n2 = tid >> 2, hg = tid & 3;
        float wzd[8];
        #pragma unroll
        for (int j = 0; j < 8; ++j) wzd[j] = Wfz[H * H + hg * 8 + j];
        float acc[8];
        #pragma unroll
        for (int j = 0; j < 8; ++j) acc[j] = 0.f;
        const float* drow = d2 + (long)n2 * E_DIM + e0;
        for (int et = 0; et < TE; et += 4) {
            const float4 d4 = *reinterpret_cast<const float4*>(drow + et);
            const float dv[4] = {d4.x, d4.y, d4.z, d4.w};
            #pragma unroll
            for (int q = 0; q < 4; ++q) {
                #pragma unroll
                for (int j = 0; j < 8; ++j)
                    acc[j] += fmaxf(fmaf(dv[q], wzd[j], vz_l[et + q][hg * 8 + j]), 0.f);
            }
        }
        float* zp = zAcc + n2 * H + hg * 8;
        #pragma unroll
        for (int j = 0; j < 8; ++j) atomicAdd(&zp[j], acc[j]);
    }
}

// ---------------- kernel D: output ----------------
__global__ __launch_bounds__(1024) void kD(
    const float* __restrict__ zAcc,
    const float* __restrict__ Wgz, const float* __restrict__ bgz,
    float* __restrict__ out)
{
    __shared__ float z_l[N1 * H];
    const int tid = threadIdx.x;
    for (int t = tid; t < N1 * H; t += 1024) z_l[t] = zAcc[t] * (1.f / E_DIM);
    __syncthreads();
    for (int t = tid; t < N1 * H; t += 1024) {
        const int n = t >> 5, h = t & 31;
        float s = bgz[h];
        #pragma unroll
        for (int k = 0; k < H; ++k) s = fmaf(z_l[n * H + k], Wgz[k * H + h], s);
        out[t] = fmaxf(s, 0.f);
    }
}

extern "C" void kernel_launch(void* const* d_in, const int* in_sizes, int n_in,
                              void* d_out, int out_size, void* d_ws, size_t ws_size,
                              hipStream_t stream)
{
    const float* sup  = (const float*)d_in[0];
    const int*   lab  = (const int*)d_in[1];
    const float* qry  = (const float*)d_in[2];
    const float* Wfvb = (const float*)d_in[3];
    const float* bfvb = (const float*)d_in[4];
    const float* Wgvb = (const float*)d_in[5];
    const float* bgvb = (const float*)d_in[6];
    const float* Wfu  = (const float*)d_in[7];
    const float* bfu  = (const float*)d_in[8];
    const float* Wgu  = (const float*)d_in[9];
    const float* bgu  = (const float*)d_in[10];
    const float* Wfvc = (const float*)d_in[11];
    const float* bfvc = (const float*)d_in[12];
    const float* Wgvc = (const float*)d_in[13];
    const float* bgvc = (const float*)d_in[14];
    const float* Wfz  = (const float*)d_in[15];
    const float* bfz  = (const float*)d_in[16];
    const float* Wgz  = (const float*)d_in[17];
    const float* bgz  = (const float*)d_in[18];

    float* out = (float*)d_out;

    float* alphaAcc = (float*)d_ws;          // 1920 floats
    float* zAcc     = alphaAcc + N1 * H;     // 1920 floats
    float* uwb      = zAcc + N1 * H;         // 1920 floats

    (void)hipMemsetAsync(alphaAcc, 0, 2 * N1 * H * sizeof(float), stream);

    kA<<<NBLK, 256, 0, stream>>>(sup, Wfvb, bfvb, Wgvb, bgvb, Wfu, bfu, alphaAcc);
    kB<<<1, 1024, 0, stream>>>(alphaAcc, lab, Wfvb, bfvb, Wgvb, bgvb, Wfu, bfu,
                               Wgu, bgu, Wfvc, bfvc, uwb);
    kC<<<NBLK, 256, 0, stream>>>(sup, qry, uwb, Wfvc, Wgvc, bgvc, Wfz, bfz, zAcc);
    kD<<<1, 1024, 0, stream>>>(zAcc, Wgz, bgz, out);
}

// Round 3
// 111.619 us; speedup vs baseline: 2.0913x; 2.0913x over previous
//
#include <hip/hip_runtime.h>

#define E_DIM 69120
#define N1 60
#define H 32
#define CC 3
#define TEB 64
#define NB2 (E_DIM / TEB)   // 1080
#define DS_STRIDE 68        // pad: rows 16B-aligned, banks rotate by 4/row
#define PSZ (N1 * H)        // 1920
#define TE 256
#define NBLK (E_DIM / TE)   // 270 (fallback path)

// =====================================================================
// Main path: high-occupancy kernels, partial-sum buffers (no atomics)
// =====================================================================

template<bool ATOMIC>
__global__ __launch_bounds__(256) void kA2(
    const float* __restrict__ d,
    const float* __restrict__ Wfvb, const float* __restrict__ bfvb,
    const float* __restrict__ Wgvb, const float* __restrict__ bgvb,
    const float* __restrict__ Wfu,  const float* __restrict__ bfu,
    float* __restrict__ outp)       // ATOMIC ? acc[1920] : part[NB2][1920]
{
    __shared__ float ds[N1][DS_STRIDE];
    __shared__ float bufA[TEB][H + 1];
    __shared__ float bufB[TEB][H + 1];
    __shared__ float bufT[H][DS_STRIDE];
    const int tid = threadIdx.x;
    const int sE = blockIdx.x * TEB;

    for (int i = tid; i < N1 * (TEB / 4); i += 256) {
        const int n = i >> 4, c = (i & 15) * 4;
        const float4 v = *reinterpret_cast<const float4*>(d + (long)n * E_DIM + sE + c);
        *reinterpret_cast<float4*>(&ds[n][c]) = v;
    }
    __syncthreads();

    const int eLoc = tid & 63, hg = tid >> 6, h0 = hg * 8;

    {
        float wf[8], bf[8], t1[8];
        #pragma unroll
        for (int j = 0; j < 8; ++j) { wf[j] = Wfvb[h0 + j]; bf[j] = bfvb[h0 + j]; t1[j] = 0.f; }
        for (int n = 0; n < N1; ++n) {
            const float dv = ds[n][eLoc];
            #pragma unroll
            for (int j = 0; j < 8; ++j) t1[j] += fmaxf(fmaf(dv, wf[j], bf[j]), 0.f);
        }
        #pragma unroll
        for (int j = 0; j < 8; ++j) bufA[eLoc][h0 + j] = t1[j] * (1.f / N1);
    }
    __syncthreads();

    {
        float acc[8];
        #pragma unroll
        for (int j = 0; j < 8; ++j) acc[j] = bgvb[h0 + j];
        #pragma unroll
        for (int k = 0; k < H; ++k) {
            const float t = bufA[eLoc][k];
            #pragma unroll
            for (int j = 0; j < 8; ++j) acc[j] = fmaf(t, Wgvb[k * H + h0 + j], acc[j]);
        }
        #pragma unroll
        for (int j = 0; j < 8; ++j) bufB[eLoc][h0 + j] = fmaxf(acc[j], 0.f);
    }
    __syncthreads();

    {
        float acc[8];
        #pragma unroll
        for (int j = 0; j < 8; ++j) acc[j] = bfu[h0 + j];
        #pragma unroll
        for (int k = 0; k < H; ++k) {
            const float t = bufB[eLoc][k];
            #pragma unroll
            for (int j = 0; j < 8; ++j) acc[j] = fmaf(t, Wfu[k * H + h0 + j], acc[j]);
        }
        #pragma unroll
        for (int j = 0; j < 8; ++j) bufT[h0 + j][eLoc] = acc[j];
    }
    __syncthreads();

    if (tid < N1 * 4) {
        const int n = tid >> 2, g = tid & 3, hb = g * 8;
        float wud[8], acc[8];
        #pragma unroll
        for (int j = 0; j < 8; ++j) { wud[j] = Wfu[H * H + hb + j]; acc[j] = 0.f; }
        for (int e4 = 0; e4 < TEB; e4 += 4) {
            const float4 d4 = *reinterpret_cast<const float4*>(&ds[n][e4]);
            #pragma unroll
            for (int j = 0; j < 8; ++j) {
                const float4 w4 = *reinterpret_cast<const float4*>(&bufT[hb + j][e4]);
                acc[j] += fmaxf(fmaf(d4.x, wud[j], w4.x), 0.f)
                        + fmaxf(fmaf(d4.y, wud[j], w4.y), 0.f)
                        + fmaxf(fmaf(d4.z, wud[j], w4.z), 0.f)
                        + fmaxf(fmaf(d4.w, wud[j], w4.w), 0.f);
            }
        }
        if (ATOMIC) {
            float* p = outp + tid * 8;
            #pragma unroll
            for (int j = 0; j < 8; ++j) atomicAdd(&p[j], acc[j]);
        } else {
            float* p = outp + (long)blockIdx.x * PSZ + tid * 8;
            #pragma unroll
            for (int j = 0; j < 8; ++j) p[j] = acc[j];
        }
    }
}

__global__ __launch_bounds__(256) void kC1(
    const float* __restrict__ d, const float* __restrict__ uwb,
    const float* __restrict__ Wfvc,
    const float* __restrict__ Wgvc, const float* __restrict__ bgvc,
    const float* __restrict__ Wfz,  const float* __restrict__ bfz,
    float* __restrict__ vzT)
{
    __shared__ float ds[N1][DS_STRIDE];
    __shared__ float u_l[N1][H];
    __shared__ float bufA[TEB][H + 1];
    __shared__ float bufB[TEB][H + 1];
    const int tid = threadIdx.x;
    const int sE = blockIdx.x * TEB;

    for (int i = tid; i < N1 * (TEB / 4); i += 256) {
        const int n = i >> 4, c = (i & 15) * 4;
        const float4 v = *reinterpret_cast<const float4*>(d + (long)n * E_DIM + sE + c);
        *reinterpret_cast<float4*>(&ds[n][c]) = v;
    }
    for (int i = tid; i < (N1 * H) / 4; i += 256)
        reinterpret_cast<float4*>(&u_l[0][0])[i] = reinterpret_cast<const float4*>(uwb)[i];
    __syncthreads();

    const int eLoc = tid & 63, hg = tid >> 6, h0 = hg * 8;

    {
        float wvd[8], m[8];
        #pragma unroll
        for (int j = 0; j < 8; ++j) { wvd[j] = Wfvc[H * H + h0 + j]; m[j] = 0.f; }
        for (int n = 0; n < N1; ++n) {
            const float dv = ds[n][eLoc];
            const float4 u0 = *reinterpret_cast<const float4*>(&u_l[n][h0]);
            const float4 u1 = *reinterpret_cast<const float4*>(&u_l[n][h0 + 4]);
            const float ub[8] = {u0.x, u0.y, u0.z, u0.w, u1.x, u1.y, u1.z, u1.w};
            #pragma unroll
            for (int j = 0; j < 8; ++j) m[j] += fmaxf(fmaf(dv, wvd[j], ub[j]), 0.f);
        }
        #pragma unroll
        for (int j = 0; j < 8; ++j) bufA[eLoc][h0 + j] = m[j] * (1.f / N1);
    }
    __syncthreads();

    {
        float acc[8];
        #pragma unroll
        for (int j = 0; j < 8; ++j) acc[j] = bgvc[h0 + j];
        #pragma unroll
        for (int k = 0; k < H; ++k) {
            const float t = bufA[eLoc][k];
            #pragma unroll
            for (int j = 0; j < 8; ++j) acc[j] = fmaf(t, Wgvc[k * H + h0 + j], acc[j]);
        }
        #pragma unroll
        for (int j = 0; j < 8; ++j) bufB[eLoc][h0 + j] = fmaxf(acc[j], 0.f);
    }
    __syncthreads();

    {
        float acc[8];
        #pragma unroll
        for (int j = 0; j < 8; ++j) acc[j] = bfz[h0 + j];
        #pragma unroll
        for (int k = 0; k < H; ++k) {
            const float t = bufB[eLoc][k];
            #pragma unroll
            for (int j = 0; j < 8; ++j) acc[j] = fmaf(t, Wfz[k * H + h0 + j], acc[j]);
        }
        #pragma unroll
        for (int j = 0; j < 8; ++j) vzT[(long)(h0 + j) * E_DIM + sE + eLoc] = acc[j];
    }
}

template<bool ATOMIC>
__global__ __launch_bounds__(256) void kC2(
    const float* __restrict__ d2, const float* __restrict__ vzT,
    const float* __restrict__ Wfz,
    float* __restrict__ outp)
{
    __shared__ float ds2[N1][DS_STRIDE];
    __shared__ float bufT[H][DS_STRIDE];
    const int tid = threadIdx.x;
    const int sE = blockIdx.x * TEB;

    for (int i = tid; i < N1 * (TEB / 4); i += 256) {
        const int n = i >> 4, c = (i & 15) * 4;
        const float4 v = *reinterpret_cast<const float4*>(d2 + (long)n * E_DIM + sE + c);
        *reinterpret_cast<float4*>(&ds2[n][c]) = v;
    }
    for (int i = tid; i < H * (TEB / 4); i += 256) {
        const int h = i >> 4, e4 = (i & 15) * 4;
        const float4 v = *reinterpret_cast<const float4*>(vzT + (long)h * E_DIM + sE + e4);
        *reinterpret_cast<float4*>(&bufT[h][e4]) = v;
    }
    __syncthreads();

    if (tid < N1 * 4) {
        const int n = tid >> 2, g = tid & 3, hb = g * 8;
        float wzd[8], acc[8];
        #pragma unroll
        for (int j = 0; j < 8; ++j) { wzd[j] = Wfz[H * H + hb + j]; acc[j] = 0.f; }
        for (int e4 = 0; e4 < TEB; e4 += 4) {
            const float4 d4 = *reinterpret_cast<const float4*>(&ds2[n][e4]);
            #pragma unroll
            for (int j = 0; j < 8; ++j) {
                const float4 w4 = *reinterpret_cast<const float4*>(&bufT[hb + j][e4]);
                acc[j] += fmaxf(fmaf(d4.x, wzd[j], w4.x), 0.f)
                        + fmaxf(fmaf(d4.y, wzd[j], w4.y), 0.f)
                        + fmaxf(fmaf(d4.z, wzd[j], w4.z), 0.f)
                        + fmaxf(fmaf(d4.w, wzd[j], w4.w), 0.f);
            }
        }
        if (ATOMIC) {
            float* p = outp + tid * 8;
            #pragma unroll
            for (int j = 0; j < 8; ++j) atomicAdd(&p[j], acc[j]);
        } else {
            float* p = outp + (long)blockIdx.x * PSZ + tid * 8;
            #pragma unroll
            for (int j = 0; j < 8; ++j) p[j] = acc[j];
        }
    }
}

__global__ __launch_bounds__(256) void kR(
    const float* __restrict__ part, float* __restrict__ out)
{
    __shared__ float red[16][17];
    const int tid = threadIdx.x;
    const int oLoc = tid & 15, c = tid >> 4;
    const int o = blockIdx.x * 16 + oLoc;
    const int b0 = c * 68;
    const int bN = (NB2 - b0 < 68) ? (NB2 - b0) : 68;
    const float* p = part + (long)b0 * PSZ + o;
    float s = 0.f;
    #pragma unroll 4
    for (int b = 0; b < bN; ++b) s += p[(long)b * PSZ];
    red[c][oLoc] = s;
    __syncthreads();
    if (tid < 16) {
        float t = 0.f;
        #pragma unroll
        for (int ci = 0; ci < 16; ++ci) t += red[ci][tid];
        out[blockIdx.x * 16 + tid] = t;
    }
}

__global__ __launch_bounds__(1024) void kB(
    const float* __restrict__ alphaAcc, const int* __restrict__ label,
    const float* __restrict__ Wfvb, const float* __restrict__ bfvb,
    const float* __restrict__ Wgvb, const float* __restrict__ bgvb,
    const float* __restrict__ Wfu,  const float* __restrict__ bfu,
    const float* __restrict__ Wgu,  const float* __restrict__ bgu,
    const float* __restrict__ Wfvc, const float* __restrict__ bfvc,
    float* __restrict__ uwb)
{
    __shared__ float up_l[N1 * H];
    __shared__ float un_l[N1 * H];
    __shared__ float cb_l[CC * H];
    __shared__ float cw_l[CC * H];
    __shared__ int   cnt[CC];
    const int tid = threadIdx.x;

    if (tid < CC) cnt[tid] = 0;
    __syncthreads();
    if (tid < N1) atomicAdd(&cnt[label[tid]], 1);
    __syncthreads();

    if (tid < CC * H) {
        const int c = tid / H, h = tid % H;
        const float nc = (float)cnt[c];
        float s = bgvb[h];
        #pragma unroll
        for (int k = 0; k < H; ++k) {
            const float t1c = (nc * fmaxf(Wfvb[k] + bfvb[k], 0.f) +
                               ((float)N1 - nc) * fmaxf(bfvb[k], 0.f)) * (1.f / N1);
            s = fmaf(t1c, Wgvb[k * H + h], s);
        }
        cb_l[tid] = fmaxf(s, 0.f);
    }
    __syncthreads();
    if (tid < CC * H) {
        const int c = tid / H, h = tid % H;
        float s = bfu[h];
        #pragma unroll
        for (int k = 0; k < H; ++k) s = fmaf(cb_l[c * H + k], Wfu[k * H + h], s);
        cw_l[tid] = s;
    }
    __syncthreads();
    for (int t = tid; t < N1 * H; t += 1024) {
        const int n = t >> 5, h = t & 31;
        const int ln = label[n];
        const float wud = Wfu[H * H + h];
        float s = 0.f;
        #pragma unroll
        for (int c = 0; c < CC; ++c)
            s += fmaxf(cw_l[c * H + h] + ((c == ln) ? wud : 0.f), 0.f);
        up_l[t] = alphaAcc[t] * (1.f / E_DIM) + s * (1.f / CC);
    }
    __syncthreads();
    for (int t = tid; t < N1 * H; t += 1024) {
        const int n = t >> 5, h = t & 31;
        float s = bgu[h];
        #pragma unroll
        for (int k = 0; k < H; ++k) s = fmaf(up_l[n * H + k], Wgu[k * H + h], s);
        un_l[t] = fmaxf(s, 0.f);
    }
    __syncthreads();
    for (int t = tid; t < N1 * H; t += 1024) {
        const int n = t >> 5, h = t & 31;
        float s = bfvc[h];
        #pragma unroll
        for (int k = 0; k < H; ++k) s = fmaf(un_l[n * H + k], Wfvc[k * H + h], s);
        uwb[t] = s;
    }
}

__global__ __launch_bounds__(1024) void kD(
    const float* __restrict__ zAcc,
    const float* __restrict__ Wgz, const float* __restrict__ bgz,
    float* __restrict__ out)
{
    __shared__ float z_l[N1 * H];
    const int tid = threadIdx.x;
    for (int t = tid; t < N1 * H; t += 1024) z_l[t] = zAcc[t] * (1.f / E_DIM);
    __syncthreads();
    for (int t = tid; t < N1 * H; t += 1024) {
        const int n = t >> 5, h = t & 31;
        float s = bgz[h];
        #pragma unroll
        for (int k = 0; k < H; ++k) s = fmaf(z_l[n * H + k], Wgz[k * H + h], s);
        out[t] = fmaxf(s, 0.f);
    }
}

// =====================================================================
// Fallback (round-2 proven): one thread per e, atomics
// =====================================================================
__global__ __launch_bounds__(256) void kA0(
    const float* __restrict__ d,
    const float* __restrict__ Wfvb, const float* __restrict__ bfvb,
    const float* __restrict__ Wgvb, const float* __restrict__ bgvb,
    const float* __restrict__ Wfu,  const float* __restrict__ bfu,
    float* __restrict__ alphaAcc)
{
    __shared__ float vw_l[TE][H + 1];
    const int tid = threadIdx.x;
    const long e0 = (long)blockIdx.x * TE;
    {
        const long e = e0 + tid;
        float wf[H], bf[H];
        #pragma unroll
        for (int h = 0; h < H; ++h) { wf[h] = Wfvb[h]; bf[h] = bfvb[h]; }
        float t1[H];
        #pragma unroll
        for (int h = 0; h < H; ++h) t1[h] = 0.f;
        for (int n = 0; n < N1; ++n) {
            const float dv = d[(long)n * E_DIM + e];
            #pragma unroll
            for (int h = 0; h < H; ++h) t1[h] += fmaxf(fmaf(dv, wf[h], bf[h]), 0.f);
        }
        #pragma unroll
        for (int h = 0; h < H; ++h) t1[h] *= (1.f / N1);
        float vb[H];
        #pragma unroll
        for (int h = 0; h < H; ++h) vb[h] = bgvb[h];
        #pragma unroll
        for (int k = 0; k < H; ++k) {
            const float t = t1[k];
            #pragma unroll
            for (int h = 0; h < H; ++h) vb[h] = fmaf(t, Wgvb[k * H + h], vb[h]);
        }
        #pragma unroll
        for (int h = 0; h < H; ++h) vb[h] = fmaxf(vb[h], 0.f);
        float vw[H];
        #pragma unroll
        for (int h = 0; h < H; ++h) vw[h] = bfu[h];
        #pragma unroll
        for (int k = 0; k < H; ++k) {
            const float t = vb[k];
            #pragma unroll
            for (int h = 0; h < H; ++h) vw[h] = fmaf(t, Wfu[k * H + h], vw[h]);
        }
        #pragma unroll
        for (int h = 0; h < H; ++h) vw_l[tid][h] = vw[h];
    }
    __syncthreads();
    if (tid < N1 * 4) {
        const int n = tid >> 2, hg = tid & 3;
        float wud[8];
        #pragma unroll
        for (int j = 0; j < 8; ++j) wud[j] = Wfu[H * H + hg * 8 + j];
        float acc[8];
        #pragma unroll
        for (int j = 0; j < 8; ++j) acc[j] = 0.f;
        const float* drow = d + (long)n * E_DIM + e0;
        for (int et = 0; et < TE; et += 4) {
            const float4 d4 = *reinterpret_cast<const float4*>(drow + et);
            const float dv[4] = {d4.x, d4.y, d4.z, d4.w};
            #pragma unroll
            for (int q = 0; q < 4; ++q) {
                #pragma unroll
                for (int j = 0; j < 8; ++j)
                    acc[j] += fmaxf(fmaf(dv[q], wud[j], vw_l[et + q][hg * 8 + j]), 0.f);
            }
        }
        float* ap = alphaAcc + n * H + hg * 8;
        #pragma unroll
        for (int j = 0; j < 8; ++j) atomicAdd(&ap[j], acc[j]);
    }
}

__global__ __launch_bounds__(256) void kC0(
    const float* __restrict__ d, const float* __restrict__ d2,
    const float* __restrict__ uwb,
    const float* __restrict__ Wfvc,
    const float* __restrict__ Wgvc, const float* __restrict__ bgvc,
    const float* __restrict__ Wfz,  const float* __restrict__ bfz,
    float* __restrict__ zAcc)
{
    __shared__ float vz_l[TE][H + 1];
    const int tid = threadIdx.x;
    const long e0 = (long)blockIdx.x * TE;
    {
        const long e = e0 + tid;
        float wvd[H];
        #pragma unroll
        for (int h = 0; h < H; ++h) wvd[h] = Wfvc[H * H + h];
        float m[H];
        #pragma unroll
        for (int h = 0; h < H; ++h) m[h] = 0.f;
        for (int n = 0; n < N1; ++n) {
            const float dv = d[(long)n * E_DIM + e];
            const float* ur = uwb + n * H;
            #pragma unroll
            for (int h = 0; h < H; ++h) m[h] += fmaxf(fmaf(dv, wvd[h], ur[h]), 0.f);
        }
        #pragma unroll
        for (int h = 0; h < H; ++h) m[h] *= (1.f / N1);
        float v[H];
        #pragma unroll
        for (int h = 0; h < H; ++h) v[h] = bgvc[h];
        #pragma unroll
        for (int k = 0; k < H; ++k) {
            const float t = m[k];
            #pragma unroll
            for (int h = 0; h < H; ++h) v[h] = fmaf(t, Wgvc[k * H + h], v[h]);
        }
        #pragma unroll
        for (int h = 0; h < H; ++h) v[h] = fmaxf(v[h], 0.f);
        float vz[H];
        #pragma unroll
        for (int h = 0; h < H; ++h) vz[h] = bfz[h];
        #pragma unroll
        for (int k = 0; k < H; ++k) {
            const float t = v[k];
            #pragma unroll
            for (int h = 0; h < H; ++h) vz[h] = fmaf(t, Wfz[k * H + h], vz[h]);
        }
        #pragma unroll
        for (int h = 0; h < H; ++h) vz_l[tid][h] = vz[h];
    }
    __syncthreads();
    if (tid < N1 * 4) {
        const int n2 = tid >> 2, hg = tid & 3;
        float wzd[8];
        #pragma unroll
        for (int j = 0; j < 8; ++j) wzd[j] = Wfz[H * H + hg * 8 + j];
        float acc[8];
        #pragma unroll
        for (int j = 0; j < 8; ++j) acc[j] = 0.f;
        const float* drow = d2 + (long)n2 * E_DIM + e0;
        for (int et = 0; et < TE; et += 4) {
            const float4 d4 = *reinterpret_cast<const float4*>(drow + et);
            const float dv[4] = {d4.x, d4.y, d4.z, d4.w};
            #pragma unroll
            for (int q = 0; q < 4; ++q) {
                #pragma unroll
                for (int j = 0; j < 8; ++j)
                    acc[j] += fmaxf(fmaf(dv[q], wzd[j], vz_l[et + q][hg * 8 + j]), 0.f);
            }
        }
        float* zp = zAcc + n2 * H + hg * 8;
        #pragma unroll
        for (int j = 0; j < 8; ++j) atomicAdd(&zp[j], acc[j]);
    }
}

extern "C" void kernel_launch(void* const* d_in, const int* in_sizes, int n_in,
                              void* d_out, int out_size, void* d_ws, size_t ws_size,
                              hipStream_t stream)
{
    const float* sup  = (const float*)d_in[0];
    const int*   lab  = (const int*)d_in[1];
    const float* qry  = (const float*)d_in[2];
    const float* Wfvb = (const float*)d_in[3];
    const float* bfvb = (const float*)d_in[4];
    const float* Wgvb = (const float*)d_in[5];
    const float* bgvb = (const float*)d_in[6];
    const float* Wfu  = (const float*)d_in[7];
    const float* bfu  = (const float*)d_in[8];
    const float* Wgu  = (const float*)d_in[9];
    const float* bgu  = (const float*)d_in[10];
    const float* Wfvc = (const float*)d_in[11];
    const float* bfvc = (const float*)d_in[12];
    const float* Wgvc = (const float*)d_in[13];
    const float* bgvc = (const float*)d_in[14];
    const float* Wfz  = (const float*)d_in[15];
    const float* bfz  = (const float*)d_in[16];
    const float* Wgz  = (const float*)d_in[17];
    const float* bgz  = (const float*)d_in[18];
    float* out = (float*)d_out;

    float* alphaAcc = (float*)d_ws;
    float* zAcc     = alphaAcc + PSZ;
    float* uwb      = zAcc + PSZ;
    float* partA    = uwb + PSZ;
    float* partZ    = partA + (size_t)NB2 * PSZ;
    float* vzT      = partZ + (size_t)NB2 * PSZ;

    const size_t needMain = (3 * (size_t)PSZ + 2 * (size_t)NB2 * PSZ + (size_t)E_DIM * H) * sizeof(float);
    const size_t needMid  = (3 * (size_t)PSZ + (size_t)E_DIM * H) * sizeof(float);

    if (ws_size >= needMain) {
        kA2<false><<<NB2, 256, 0, stream>>>(sup, Wfvb, bfvb, Wgvb, bgvb, Wfu, bfu, partA);
        kR<<<PSZ / 16, 256, 0, stream>>>(partA, alphaAcc);
        kB<<<1, 1024, 0, stream>>>(alphaAcc, lab, Wfvb, bfvb, Wgvb, bgvb, Wfu, bfu,
                                   Wgu, bgu, Wfvc, bfvc, uwb);
        kC1<<<NB2, 256, 0, stream>>>(sup, uwb, Wfvc, Wgvc, bgvc, Wfz, bfz, vzT);
        kC2<false><<<NB2, 256, 0, stream>>>(qry, vzT, Wfz, partZ);
        kR<<<PSZ / 16, 256, 0, stream>>>(partZ, zAcc);
        kD<<<1, 1024, 0, stream>>>(zAcc, Wgz, bgz, out);
    } else if (ws_size >= needMid) {
        float* vzT2 = partA;
        (void)hipMemsetAsync(alphaAcc, 0, 2 * PSZ * sizeof(float), stream);
        kA2<true><<<NB2, 256, 0, stream>>>(sup, Wfvb, bfvb, Wgvb, bgvb, Wfu, bfu, alphaAcc);
        kB<<<1, 1024, 0, stream>>>(alphaAcc, lab, Wfvb, bfvb, Wgvb, bgvb, Wfu, bfu,
                                   Wgu, bgu, Wfvc, bfvc, uwb);
        kC1<<<NB2, 256, 0, stream>>>(sup, uwb, Wfvc, Wgvc, bgvc, Wfz, bfz, vzT2);
        kC2<true><<<NB2, 256, 0, stream>>>(qry, vzT2, Wfz, zAcc);
        kD<<<1, 1024, 0, stream>>>(zAcc, Wgz, bgz, out);
    } else {
        (void)hipMemsetAsync(alphaAcc, 0, 2 * PSZ * sizeof(float), stream);
        kA0<<<NBLK, 256, 0, stream>>>(sup, Wfvb, bfvb, Wgvb, bgvb, Wfu, bfu, alphaAcc);
        kB<<<1, 1024, 0, stream>>>(alphaAcc, lab, Wfvb, bfvb, Wgvb, bgvb, Wfu, bfu,
                                   Wgu, bgu, Wfvc, bfvc, uwb);
        kC0<<<NBLK, 256, 0, stream>>>(sup, qry, uwb, Wfvc, Wgvc, bgvc, Wfz, bfz, zAcc);
        kD<<<1, 1024, 0, stream>>>(zAcc, Wgz, bgz, out);
    }
}

// Round 4
// 106.197 us; speedup vs baseline: 2.1981x; 1.0511x over previous
//
#include <hip/hip_runtime.h>

#define E_DIM 69120
#define N1 60
#define H 32
#define CC 3
#define TEB 64
#define NB2 (E_DIM / TEB)   // 1080
#define SDS 65              // ds stride (floats): scalar access, (n+e)%32 banks
#define SBT 66              // bufT stride (floats): rows 8B-aligned, b64 reads 2-way max
#define PSZ (N1 * H)        // 1920

#define OFF_R2 (N1 * SDS * 4)           // 15600, 16B-aligned
#define OFF_R3 (OFF_R2 + 64 * 33 * 4)   // 24048, 16B-aligned
#define SMEM_SZ (OFF_R3 + 64 * 33 * 4)  // 32496 -> 5 blocks/CU

// =====================================================================
// kA3: v_bar chain + alpha partials.   LDS: ds | bufA/bufT | bufB
// =====================================================================
template<bool ATOMIC>
__global__ __launch_bounds__(256, 4) void kA3(
    const float* __restrict__ d,
    const float* __restrict__ Wfvb, const float* __restrict__ bfvb,
    const float* __restrict__ Wgvb, const float* __restrict__ bgvb,
    const float* __restrict__ Wfu,  const float* __restrict__ bfu,
    float* __restrict__ outp)
{
    __shared__ __align__(16) char smem[SMEM_SZ];
    float* dsf        = (float*)smem;                    // [N1][SDS]
    float (*bufA)[33] = (float(*)[33])(smem + OFF_R2);   // [64][33]
    float (*bufB)[33] = (float(*)[33])(smem + OFF_R3);   // [64][33]
    float* bufT       = (float*)(smem + OFF_R2);         // [32][SBT] overlays bufA
    const int tid = threadIdx.x;
    const long sE = (long)blockIdx.x * TEB;

    // stage d-tile (coalesced float4 global -> scalar LDS, conflict-free)
    for (int i = tid; i < N1 * (TEB / 4); i += 256) {
        const int n = i >> 4, c = (i & 15) * 4;
        const float4 v = *(const float4*)(d + (long)n * E_DIM + sE + c);
        float* w = dsf + n * SDS + c;
        w[0] = v.x; w[1] = v.y; w[2] = v.z; w[3] = v.w;
    }
    __syncthreads();

    const int eLoc = tid & 63, h0 = (tid >> 6) * 8;

    // stage 1: t1 = mean_n relu(d*wf + bf)  -> bufA (scaled)
    {
        float wf[8], bf[8], t1[8];
        #pragma unroll
        for (int j = 0; j < 8; ++j) { wf[j] = Wfvb[h0+j]; bf[j] = bfvb[h0+j]; t1[j] = 0.f; }
        const float* dp = dsf + eLoc;
        #pragma unroll 4
        for (int n = 0; n < N1; ++n) {
            const float dv = dp[n * SDS];
            #pragma unroll
            for (int j = 0; j < 8; ++j) t1[j] += fmaxf(fmaf(dv, wf[j], bf[j]), 0.f);
        }
        #pragma unroll
        for (int j = 0; j < 8; ++j) bufA[eLoc][h0+j] = t1[j] * (1.f / N1);
    }
    __syncthreads();

    // mv1: vb = relu(t1 @ Wgvb + bgvb) -> bufB
    {
        float acc[8];
        #pragma unroll
        for (int j = 0; j < 8; ++j) acc[j] = bgvb[h0+j];
        #pragma unroll
        for (int k = 0; k < H; ++k) {
            const float t = bufA[eLoc][k];
            #pragma unroll
            for (int j = 0; j < 8; ++j) acc[j] = fmaf(t, Wgvb[k*H + h0+j], acc[j]);
        }
        #pragma unroll
        for (int j = 0; j < 8; ++j) bufB[eLoc][h0+j] = fmaxf(acc[j], 0.f);
    }
    __syncthreads();

    // mv2: vw = vb @ Wu_v + b_fu -> bufT (transposed; bufA is dead)
    {
        float acc[8];
        #pragma unroll
        for (int j = 0; j < 8; ++j) acc[j] = bfu[h0+j];
        #pragma unroll
        for (int k = 0; k < H; ++k) {
            const float t = bufB[eLoc][k];
            #pragma unroll
            for (int j = 0; j < 8; ++j) acc[j] = fmaf(t, Wfu[k*H + h0+j], acc[j]);
        }
        #pragma unroll
        for (int j = 0; j < 8; ++j) bufT[(h0+j)*SBT + eLoc] = acc[j];
    }
    __syncthreads();

    // stage 2: alpha partials; d re-read from GLOBAL (L2-hot)
    if (tid < N1 * 4) {
        const int n = tid >> 2, hb = (tid & 3) * 8;
        float wud[8], acc[8];
        #pragma unroll
        for (int j = 0; j < 8; ++j) { wud[j] = Wfu[H*H + hb + j]; acc[j] = 0.f; }
        const float* drow = d + (long)n * E_DIM + sE;
        for (int e4 = 0; e4 < TEB; e4 += 4) {
            const float4 d4 = *(const float4*)(drow + e4);
            #pragma unroll
            for (int j = 0; j < 8; ++j) {
                const float* wr = bufT + (hb + j) * SBT + e4;
                const float2 wa = *(const float2*)(wr);
                const float2 wb = *(const float2*)(wr + 2);
                acc[j] += fmaxf(fmaf(d4.x, wud[j], wa.x), 0.f)
                        + fmaxf(fmaf(d4.y, wud[j], wa.y), 0.f)
                        + fmaxf(fmaf(d4.z, wud[j], wb.x), 0.f)
                        + fmaxf(fmaf(d4.w, wud[j], wb.y), 0.f);
            }
        }
        if (ATOMIC) {
            float* p = outp + tid * 8;
            #pragma unroll
            for (int j = 0; j < 8; ++j) atomicAdd(&p[j], acc[j]);
        } else {
            float4* p = (float4*)(outp + (long)blockIdx.x * PSZ + tid * 8);
            p[0] = make_float4(acc[0], acc[1], acc[2], acc[3]);
            p[1] = make_float4(acc[4], acc[5], acc[6], acc[7]);
        }
    }
}

// =====================================================================
// kCf: fused v-chain + z partials.  LDS: ds | bufA/bufT | u_l/bufB
// =====================================================================
template<bool ATOMIC>
__global__ __launch_bounds__(256, 4) void kCf(
    const float* __restrict__ d, const float* __restrict__ d2,
    const float* __restrict__ uwb,
    const float* __restrict__ Wfvc,
    const float* __restrict__ Wgvc, const float* __restrict__ bgvc,
    const float* __restrict__ Wfz,  const float* __restrict__ bfz,
    float* __restrict__ outp)
{
    __shared__ __align__(16) char smem[SMEM_SZ];
    float* dsf        = (float*)smem;
    float (*bufA)[33] = (float(*)[33])(smem + OFF_R2);
    float (*bufB)[33] = (float(*)[33])(smem + OFF_R3);
    float* u_l        = (float*)(smem + OFF_R3);         // [60][32] overlays bufB
    float* bufT       = (float*)(smem + OFF_R2);         // [32][SBT] overlays bufA
    const int tid = threadIdx.x;
    const long sE = (long)blockIdx.x * TEB;

    for (int i = tid; i < N1 * (TEB / 4); i += 256) {
        const int n = i >> 4, c = (i & 15) * 4;
        const float4 v = *(const float4*)(d + (long)n * E_DIM + sE + c);
        float* w = dsf + n * SDS + c;
        w[0] = v.x; w[1] = v.y; w[2] = v.z; w[3] = v.w;
    }
    for (int i = tid; i < PSZ / 4; i += 256)
        ((float4*)u_l)[i] = ((const float4*)uwb)[i];
    __syncthreads();

    const int eLoc = tid & 63, h0 = (tid >> 6) * 8;

    // stage 1: m = mean_n relu(d*wv_d + u_n) -> bufA (scaled)
    {
        float wvd[8], m[8];
        #pragma unroll
        for (int j = 0; j < 8; ++j) { wvd[j] = Wfvc[H*H + h0+j]; m[j] = 0.f; }
        const float* dp = dsf + eLoc;
        #pragma unroll 4
        for (int n = 0; n < N1; ++n) {
            const float dv = dp[n * SDS];
            const float4 u0 = *(const float4*)(u_l + n * H + h0);
            const float4 u1 = *(const float4*)(u_l + n * H + h0 + 4);
            const float ub[8] = {u0.x, u0.y, u0.z, u0.w, u1.x, u1.y, u1.z, u1.w};
            #pragma unroll
            for (int j = 0; j < 8; ++j) m[j] += fmaxf(fmaf(dv, wvd[j], ub[j]), 0.f);
        }
        #pragma unroll
        for (int j = 0; j < 8; ++j) bufA[eLoc][h0+j] = m[j] * (1.f / N1);
    }
    __syncthreads();

    // mv1: v = relu(m @ Wgvc + bgvc) -> bufB (u_l is dead)
    {
        float acc[8];
        #pragma unroll
        for (int j = 0; j < 8; ++j) acc[j] = bgvc[h0+j];
        #pragma unroll
        for (int k = 0; k < H; ++k) {
            const float t = bufA[eLoc][k];
            #pragma unroll
            for (int j = 0; j < 8; ++j) acc[j] = fmaf(t, Wgvc[k*H + h0+j], acc[j]);
        }
        #pragma unroll
        for (int j = 0; j < 8; ++j) bufB[eLoc][h0+j] = fmaxf(acc[j], 0.f);
    }
    __syncthreads();

    // mv2: vz = v @ Wz_v + b_fz -> bufT (bufA is dead)
    {
        float acc[8];
        #pragma unroll
        for (int j = 0; j < 8; ++j) acc[j] = bfz[h0+j];
        #pragma unroll
        for (int k = 0; k < H; ++k) {
            const float t = bufB[eLoc][k];
            #pragma unroll
            for (int j = 0; j < 8; ++j) acc[j] = fmaf(t, Wfz[k*H + h0+j], acc[j]);
        }
        #pragma unroll
        for (int j = 0; j < 8; ++j) bufT[(h0+j)*SBT + eLoc] = acc[j];
    }
    __syncthreads();

    // stage 2: z partials over QUERY rows (global, first touch)
    if (tid < N1 * 4) {
        const int n = tid >> 2, hb = (tid & 3) * 8;
        float wzd[8], acc[8];
        #pragma unroll
        for (int j = 0; j < 8; ++j) { wzd[j] = Wfz[H*H + hb + j]; acc[j] = 0.f; }
        const float* drow = d2 + (long)n * E_DIM + sE;
        for (int e4 = 0; e4 < TEB; e4 += 4) {
            const float4 d4 = *(const float4*)(drow + e4);
            #pragma unroll
            for (int j = 0; j < 8; ++j) {
                const float* wr = bufT + (hb + j) * SBT + e4;
                const float2 wa = *(const float2*)(wr);
                const float2 wb = *(const float2*)(wr + 2);
                acc[j] += fmaxf(fmaf(d4.x, wzd[j], wa.x), 0.f)
                        + fmaxf(fmaf(d4.y, wzd[j], wa.y), 0.f)
                        + fmaxf(fmaf(d4.z, wzd[j], wb.x), 0.f)
                        + fmaxf(fmaf(d4.w, wzd[j], wb.y), 0.f);
            }
        }
        if (ATOMIC) {
            float* p = outp + tid * 8;
            #pragma unroll
            for (int j = 0; j < 8; ++j) atomicAdd(&p[j], acc[j]);
        } else {
            float4* p = (float4*)(outp + (long)blockIdx.x * PSZ + tid * 8);
            p[0] = make_float4(acc[0], acc[1], acc[2], acc[3]);
            p[1] = make_float4(acc[4], acc[5], acc[6], acc[7]);
        }
    }
}

// reduce part[NB2][PSZ] -> out[PSZ]; grid = PSZ/16 = 120 blocks
__global__ __launch_bounds__(256) void kR(
    const float* __restrict__ part, float* __restrict__ out)
{
    __shared__ float red[16][17];
    const int tid = threadIdx.x;
    const int oLoc = tid & 15, c = tid >> 4;
    const int o = blockIdx.x * 16 + oLoc;
    const int b0 = c * 68;
    const int bN = (NB2 - b0 < 68) ? (NB2 - b0) : 68;
    const float* p = part + (long)b0 * PSZ + o;
    float s = 0.f;
    #pragma unroll 4
    for (int b = 0; b < bN; ++b) s += p[(long)b * PSZ];
    red[c][oLoc] = s;
    __syncthreads();
    if (tid < 16) {
        float t = 0.f;
        #pragma unroll
        for (int ci = 0; ci < 16; ++ci) t += red[ci][tid];
        out[blockIdx.x * 16 + tid] = t;
    }
}

__global__ __launch_bounds__(1024) void kB(
    const float* __restrict__ alphaAcc, const int* __restrict__ label,
    const float* __restrict__ Wfvb, const float* __restrict__ bfvb,
    const float* __restrict__ Wgvb, const float* __restrict__ bgvb,
    const float* __restrict__ Wfu,  const float* __restrict__ bfu,
    const float* __restrict__ Wgu,  const float* __restrict__ bgu,
    const float* __restrict__ Wfvc, const float* __restrict__ bfvc,
    float* __restrict__ uwb)
{
    __shared__ float up_l[N1 * H];
    __shared__ float un_l[N1 * H];
    __shared__ float cb_l[CC * H];
    __shared__ float cw_l[CC * H];
    __shared__ int   cnt[CC];
    const int tid = threadIdx.x;

    if (tid < CC) cnt[tid] = 0;
    __syncthreads();
    if (tid < N1) atomicAdd(&cnt[label[tid]], 1);
    __syncthreads();

    if (tid < CC * H) {
        const int c = tid / H, h = tid % H;
        const float nc = (float)cnt[c];
        float s = bgvb[h];
        #pragma unroll
        for (int k = 0; k < H; ++k) {
            const float t1c = (nc * fmaxf(Wfvb[k] + bfvb[k], 0.f) +
                               ((float)N1 - nc) * fmaxf(bfvb[k], 0.f)) * (1.f / N1);
            s = fmaf(t1c, Wgvb[k * H + h], s);
        }
        cb_l[tid] = fmaxf(s, 0.f);
    }
    __syncthreads();
    if (tid < CC * H) {
        const int c = tid / H, h = tid % H;
        float s = bfu[h];
        #pragma unroll
        for (int k = 0; k < H; ++k) s = fmaf(cb_l[c * H + k], Wfu[k * H + h], s);
        cw_l[tid] = s;
    }
    __syncthreads();
    for (int t = tid; t < N1 * H; t += 1024) {
        const int n = t >> 5, h = t & 31;
        const int ln = label[n];
        const float wud = Wfu[H * H + h];
        float s = 0.f;
        #pragma unroll
        for (int c = 0; c < CC; ++c)
            s += fmaxf(cw_l[c * H + h] + ((c == ln) ? wud : 0.f), 0.f);
        up_l[t] = alphaAcc[t] * (1.f / E_DIM) + s * (1.f / CC);
    }
    __syncthreads();
    for (int t = tid; t < N1 * H; t += 1024) {
        const int n = t >> 5, h = t & 31;
        float s = bgu[h];
        #pragma unroll
        for (int k = 0; k < H; ++k) s = fmaf(up_l[n * H + k], Wgu[k * H + h], s);
        un_l[t] = fmaxf(s, 0.f);
    }
    __syncthreads();
    for (int t = tid; t < N1 * H; t += 1024) {
        const int n = t >> 5, h = t & 31;
        float s = bfvc[h];
        #pragma unroll
        for (int k = 0; k < H; ++k) s = fmaf(un_l[n * H + k], Wfvc[k * H + h], s);
        uwb[t] = s;
    }
}

__global__ __launch_bounds__(1024) void kD(
    const float* __restrict__ zAcc,
    const float* __restrict__ Wgz, const float* __restrict__ bgz,
    float* __restrict__ out)
{
    __shared__ float z_l[N1 * H];
    const int tid = threadIdx.x;
    for (int t = tid; t < N1 * H; t += 1024) z_l[t] = zAcc[t] * (1.f / E_DIM);
    __syncthreads();
    for (int t = tid; t < N1 * H; t += 1024) {
        const int n = t >> 5, h = t & 31;
        float s = bgz[h];
        #pragma unroll
        for (int k = 0; k < H; ++k) s = fmaf(z_l[n * H + k], Wgz[k * H + h], s);
        out[t] = fmaxf(s, 0.f);
    }
}

extern "C" void kernel_launch(void* const* d_in, const int* in_sizes, int n_in,
                              void* d_out, int out_size, void* d_ws, size_t ws_size,
                              hipStream_t stream)
{
    const float* sup  = (const float*)d_in[0];
    const int*   lab  = (const int*)d_in[1];
    const float* qry  = (const float*)d_in[2];
    const float* Wfvb = (const float*)d_in[3];
    const float* bfvb = (const float*)d_in[4];
    const float* Wgvb = (const float*)d_in[5];
    const float* bgvb = (const float*)d_in[6];
    const float* Wfu  = (const float*)d_in[7];
    const float* bfu  = (const float*)d_in[8];
    const float* Wgu  = (const float*)d_in[9];
    const float* bgu  = (const float*)d_in[10];
    const float* Wfvc = (const float*)d_in[11];
    const float* bfvc = (const float*)d_in[12];
    const float* Wgvc = (const float*)d_in[13];
    const float* bgvc = (const float*)d_in[14];
    const float* Wfz  = (const float*)d_in[15];
    const float* bfz  = (const float*)d_in[16];
    const float* Wgz  = (const float*)d_in[17];
    const float* bgz  = (const float*)d_in[18];
    float* out = (float*)d_out;

    float* alphaAcc = (float*)d_ws;
    float* zAcc     = alphaAcc + PSZ;
    float* uwb      = zAcc + PSZ;
    float* partA    = uwb + PSZ;
    float* partZ    = partA + (size_t)NB2 * PSZ;

    const size_t needMain = (3 * (size_t)PSZ + 2 * (size_t)NB2 * PSZ) * sizeof(float);

    if (ws_size >= needMain) {
        kA3<false><<<NB2, 256, 0, stream>>>(sup, Wfvb, bfvb, Wgvb, bgvb, Wfu, bfu, partA);
        kR<<<PSZ / 16, 256, 0, stream>>>(partA, alphaAcc);
        kB<<<1, 1024, 0, stream>>>(alphaAcc, lab, Wfvb, bfvb, Wgvb, bgvb, Wfu, bfu,
                                   Wgu, bgu, Wfvc, bfvc, uwb);
        kCf<false><<<NB2, 256, 0, stream>>>(sup, qry, uwb, Wfvc, Wgvc, bgvc, Wfz, bfz, partZ);
        kR<<<PSZ / 16, 256, 0, stream>>>(partZ, zAcc);
        kD<<<1, 1024, 0, stream>>>(zAcc, Wgz, bgz, out);
    } else {
        (void)hipMemsetAsync(alphaAcc, 0, 2 * PSZ * sizeof(float), stream);
        kA3<true><<<NB2, 256, 0, stream>>>(sup, Wfvb, bfvb, Wgvb, bgvb, Wfu, bfu, alphaAcc);
        kB<<<1, 1024, 0, stream>>>(alphaAcc, lab, Wfvb, bfvb, Wgvb, bgvb, Wfu, bfu,
                                   Wgu, bgu, Wfvc, bfvc, uwb);
        kCf<true><<<NB2, 256, 0, stream>>>(sup, qry, uwb, Wfvc, Wgvc, bgvc, Wfz, bfz, zAcc);
        kD<<<1, 1024, 0, stream>>>(zAcc, Wgz, bgz, out);
    }
}